// Round 8
// baseline (371.697 us; speedup 1.0000x reference)
//
#include <hip/hip_runtime.h>
#include <hip/hip_bf16.h>

constexpr int Bb = 2, Cc = 64, Hh = 192, Ww = 192, Gg = 4, Cg = 16;
constexpr int HW = Hh * Ww;
constexpr int BHW = Bb * HW;       // 73728
constexpr int OFFC = 72;           // G * 2 * K
constexpr int MODC = 36;           // G * K
constexpr int PT = BHW / 256;      // 288 pixel tiles (prep)

constexpr int ROLE_A_END = PT * Gg;              // 1152 offset-conv vblocks
constexpr int ROLE_B_END = ROLE_A_END + PT * 2;  // +576 mod-conv vblocks
constexpr int ROLE_C_END = ROLE_B_END + PT * Gg; // +1152 transpose vblocks
constexpr int ROLE_D_END = ROLE_C_END + 144;     // +144 pack_w vblocks

// MFMA deform geometry
constexpr int ROWB = 1168;         // LDS row pitch bytes per pixel (584 bf16; conflict-free b128)

typedef __attribute__((ext_vector_type(8))) short short8;   // 8 bf16 in 4 VGPRs
typedef __attribute__((ext_vector_type(4))) float f32x4;

__device__ __forceinline__ float sigm(float x) { return 1.f / (1.f + __expf(-x)); }
__device__ __forceinline__ ushort f2bf(float f) {
    __hip_bfloat16 h = __float2bfloat16(f);
    union { __hip_bfloat16 h; ushort u; } x; x.h = h; return x.u;
}

// ---------------- fused prep: offset conv + mod conv + x transpose + pack_w ----------------
// LDS kept at 144*20 floats (11.5 KB) so occupancy is VGPR-limited (4 waves/SIMD), not LDS-limited.
__global__ __launch_bounds__(256) void prep_kernel(
    const float* __restrict__ warp, const float* __restrict__ srcp,
    const float* __restrict__ ow, const float* __restrict__ ob,
    const float* __restrict__ mw, const float* __restrict__ mb,
    const float* __restrict__ rw,
    float* __restrict__ off_out, float* __restrict__ modf,
    float* __restrict__ xT, ushort* __restrict__ wpk, int do_xT)
{
    __shared__ float smem[144 * 20];   // 11.5 KB
    int vb = blockIdx.x;

    if (vb < ROLE_A_END) {
        // ---- offset conv (grouped), weights staged per input-half ----
        float (*wT)[20] = (float(*)[20])smem;
        int g = vb / PT;
        int pg = (vb % PT) * 256 + threadIdx.x;
        int b = pg / HW, pix = pg % HW;
        int ho = pix / Ww, wo = pix % Ww;

        int  tidx[9];
        bool tv[9];
        #pragma unroll
        for (int kh = 0; kh < 3; ++kh)
            #pragma unroll
            for (int kw = 0; kw < 3; ++kw) {
                int ih = ho - 1 + kh, iw = wo - 1 + kw;
                bool v = ((unsigned)ih < (unsigned)Hh) && ((unsigned)iw < (unsigned)Ww);
                tv[kh * 3 + kw] = v;
                tidx[kh * 3 + kw] = v ? ih * Ww + iw : 0;
            }

        float acc[18];
        #pragma unroll
        for (int i = 0; i < 18; ++i) acc[i] = 0.f;

        for (int half = 0; half < 2; ++half) {
            __syncthreads();
            for (int idx = threadIdx.x; idx < 144 * 18; idx += 256) {
                int r = idx / 18, oo = idx % 18;
                wT[r][oo] = ow[oo * 288 + half * 144 + r];
            }
            __syncthreads();
            const float* basep = (half ? srcp : warp) + (size_t)(b * Cc + g * Cg) * HW;
            for (int ic = 0; ic < 16; ++ic) {
                const float* plane = basep + (size_t)ic * HW;
                #pragma unroll
                for (int t = 0; t < 9; ++t) {
                    float v = tv[t] ? plane[tidx[t]] : 0.f;
                    const float* wr = wT[ic * 9 + t];
                    #pragma unroll
                    for (int oo = 0; oo < 18; ++oo) acc[oo] += v * wr[oo];
                }
            }
        }
        #pragma unroll
        for (int oo = 0; oo < 18; ++oo) {
            float s = acc[oo] + ob[oo];
            off_out[(size_t)(b * OFFC + g * 18 + oo) * HW + pix] = 100.f * sigm(s) - 50.f;
        }
    } else if (vb < ROLE_B_END) {
        // ---- mod conv, weights staged per 16-input-channel chunk ----
        float (*wT)[20] = (float(*)[20])smem;
        int vb2 = vb - ROLE_A_END;
        int c0 = (vb2 / PT) * 18;
        int pg = (vb2 % PT) * 256 + threadIdx.x;
        int b = pg / HW, pix = pg % HW;
        int ho = pix / Ww, wo = pix % Ww;

        int  tidx[9];
        bool tv[9];
        #pragma unroll
        for (int kh = 0; kh < 3; ++kh)
            #pragma unroll
            for (int kw = 0; kw < 3; ++kw) {
                int ih = ho - 1 + kh, iw = wo - 1 + kw;
                bool v = ((unsigned)ih < (unsigned)Hh) && ((unsigned)iw < (unsigned)Ww);
                tv[kh * 3 + kw] = v;
                tidx[kh * 3 + kw] = v ? ih * Ww + iw : 0;
            }

        float acc[18];
        #pragma unroll
        for (int i = 0; i < 18; ++i) acc[i] = 0.f;

        for (int q = 0; q < 4; ++q) {
            __syncthreads();
            for (int idx = threadIdx.x; idx < 144 * 18; idx += 256) {
                int r = idx / 18, oo = idx % 18;
                wT[r][oo] = mw[(size_t)(c0 + oo) * 576 + q * 144 + r];
            }
            __syncthreads();
            const float* bp = warp + (size_t)(b * Cc + q * 16) * HW;
            for (int ic = 0; ic < 16; ++ic) {
                const float* plane = bp + (size_t)ic * HW;
                #pragma unroll
                for (int t = 0; t < 9; ++t) {
                    float v = tv[t] ? plane[tidx[t]] : 0.f;
                    const float* wr = wT[ic * 9 + t];
                    #pragma unroll
                    for (int oo = 0; oo < 18; ++oo) acc[oo] += v * wr[oo];
                }
            }
        }
        #pragma unroll
        for (int oo = 0; oo < 18; ++oo)
            modf[(size_t)(b * MODC + c0 + oo) * HW + pix] = 2.f * sigm(acc[oo] + mb[c0 + oo]);
    } else if (vb < ROLE_C_END) {
        // ---- x transpose [B,C,H,W] -> [B,G,HW,16] ----
        if (!do_xT) return;
        int tid = (vb - ROLE_B_END) * 256 + threadIdx.x;   // over B*G*HW
        int pix = tid % HW;
        int bg = tid / HW;
        int b = bg >> 2, g = bg & 3;
        const float* src = warp + (size_t)(b * Cc + g * Cg) * HW + pix;
        float4* dst = (float4*)(xT + (size_t)tid * 16);
        #pragma unroll
        for (int c4 = 0; c4 < 4; ++c4) {
            float4 v;
            v.x = src[(size_t)(c4 * 4 + 0) * HW];
            v.y = src[(size_t)(c4 * 4 + 1) * HW];
            v.z = src[(size_t)(c4 * 4 + 2) * HW];
            v.w = src[(size_t)(c4 * 4 + 3) * HW];
            dst[c4] = v;
        }
    } else {
        // ---- pack reg_w into fragment-linear bf16 ----
        if (!do_xT) return;
        int t = (vb - ROLE_C_END) * 256 + threadIdx.x;   // 64*576 = 36864
        if (t >= 64 * 576) return;
        int o = t / 576, jp = t % 576;
        int gk = jp >> 4, c = jp & 15;
        int g = gk / 9, k = gk % 9;
        float f = rw[(size_t)o * 576 + g * 144 + c * 9 + k];
        int w = o >> 4;
        int l = (o & 15) + (((jp & 31) >> 3) << 4);
        int s = jp >> 5, e = jp & 7;
        wpk[(((size_t)(w * 18 + s)) * 64 + l) * 8 + e] = f2bf(f);
    }
}

// ---------------- deformable conv: f32 sampling -> LDS bf16 -> MFMA GEMM ----------------
// Block = 64 pixels, 4 waves. Wave wv samples group g=wv (9 k's) for all 64 px,
// then computes output rows [16wv, 16wv+16) x 64 px with 72 MFMAs.
__global__ __launch_bounds__(256) void deform_mfma(
    const float* __restrict__ xT, const float* __restrict__ offm,
    const float* __restrict__ modf, const ushort* __restrict__ wpk,
    float* __restrict__ out)
{
    __shared__ char Vs[64 * ROWB];   // 74.75 KB
    int lane = threadIdx.x & 63;
    int wv = threadIdx.x >> 6;
    int px0 = blockIdx.x * 64;        // global pixel base (over BHW); 64 | HW
    int b = px0 / HW, pix0 = px0 % HW;

    // A-fragments: 18 k-steps, 16 B per lane, wave reads contiguous 1 KB
    short8 afrag[18];
    #pragma unroll
    for (int s = 0; s < 18; ++s)
        afrag[s] = *(const short8*)(wpk + (((size_t)(wv * 18 + s)) * 64 + lane) * 8);

    // ---- phase 1: sampling (g = wv, k = 0..8, px = lane) ----
    {
        int pix = pix0 + lane;
        int ho = pix / Ww, wo = pix % Ww;
        int g = wv;
        const float* xg = xT + (size_t)((b << 2) + g) * HW * 16;

        for (int k = 0; k < 9; ++k) {
            int oyc = b * OFFC + g * 18 + 2 * k;
            float oy = offm[(size_t)oyc * HW + pix];
            float ox = offm[(size_t)(oyc + 1) * HW + pix];
            float m  = modf[(size_t)(b * MODC + g * 9 + k) * HW + pix];
            float y = oy + (float)(k / 3) + (float)(ho - 1);
            float x = ox + (float)(k % 3) + (float)(wo - 1);
            float fy = floorf(y), fx = floorf(x);
            float ly = y - fy, lx = x - fx;
            int y0 = (int)fy, x0 = (int)fx;
            bool y0v = (unsigned)y0 < (unsigned)Hh, y1v = (unsigned)(y0 + 1) < (unsigned)Hh;
            bool x0v = (unsigned)x0 < (unsigned)Ww, x1v = (unsigned)(x0 + 1) < (unsigned)Ww;
            float w00 = (y0v && x0v) ? (1.f - ly) * (1.f - lx) * m : 0.f;
            float w01 = (y0v && x1v) ? (1.f - ly) * lx * m : 0.f;
            float w10 = (y1v && x0v) ? ly * (1.f - lx) * m : 0.f;
            float w11 = (y1v && x1v) ? ly * lx * m : 0.f;
            int iy0 = min(max(y0, 0), Hh - 1), iy1 = min(max(y0 + 1, 0), Hh - 1);
            int ix0 = min(max(x0, 0), Ww - 1), ix1 = min(max(x0 + 1, 0), Ww - 1);

            const float4* t00 = (const float4*)(xg + (size_t)(iy0 * Ww + ix0) * 16);
            const float4* t01 = (const float4*)(xg + (size_t)(iy0 * Ww + ix1) * 16);
            const float4* t10 = (const float4*)(xg + (size_t)(iy1 * Ww + ix0) * 16);
            const float4* t11 = (const float4*)(xg + (size_t)(iy1 * Ww + ix1) * 16);

            float val[16];
            #pragma unroll
            for (int c4 = 0; c4 < 4; ++c4) {
                float4 a = t00[c4], b2 = t01[c4], c2 = t10[c4], d2 = t11[c4];
                val[c4 * 4 + 0] = w00 * a.x + w01 * b2.x + w10 * c2.x + w11 * d2.x;
                val[c4 * 4 + 1] = w00 * a.y + w01 * b2.y + w10 * c2.y + w11 * d2.y;
                val[c4 * 4 + 2] = w00 * a.z + w01 * b2.z + w10 * c2.z + w11 * d2.z;
                val[c4 * 4 + 3] = w00 * a.w + w01 * b2.w + w10 * c2.w + w11 * d2.w;
            }

            short8 v0, v1;
            #pragma unroll
            for (int e = 0; e < 8; ++e) {
                v0[e] = (short)f2bf(val[e]);
                v1[e] = (short)f2bf(val[8 + e]);
            }
            int gk = g * 9 + k;
            char* dst = Vs + (size_t)lane * ROWB + gk * 32;
            *(short8*)(dst)      = v0;
            *(short8*)(dst + 16) = v1;
        }
    }
    __syncthreads();

    // ---- phase 2: GEMM, wave wv -> o rows [16wv, 16wv+16) ----
    int r = lane & 15, grp = lane >> 4;
    f32x4 acc0 = {0.f, 0.f, 0.f, 0.f}, acc1 = acc0, acc2 = acc0, acc3 = acc0;

    #pragma unroll
    for (int s = 0; s < 18; ++s) {
        const char* base = Vs + (size_t)r * ROWB + s * 64 + grp * 16;
        short8 b0 = *(const short8*)(base + 0 * 16 * ROWB);
        short8 b1 = *(const short8*)(base + 1 * 16 * ROWB);
        short8 b2 = *(const short8*)(base + 2 * 16 * ROWB);
        short8 b3 = *(const short8*)(base + 3 * 16 * ROWB);
        acc0 = __builtin_amdgcn_mfma_f32_16x16x32_bf16(afrag[s], b0, acc0, 0, 0, 0);
        acc1 = __builtin_amdgcn_mfma_f32_16x16x32_bf16(afrag[s], b1, acc1, 0, 0, 0);
        acc2 = __builtin_amdgcn_mfma_f32_16x16x32_bf16(afrag[s], b2, acc2, 0, 0, 0);
        acc3 = __builtin_amdgcn_mfma_f32_16x16x32_bf16(afrag[s], b3, acc3, 0, 0, 0);
    }

    // D[row][col]: col = lane&15 (pixel), row = (lane>>4)*4 + reg (o offset)
    #pragma unroll
    for (int reg = 0; reg < 4; ++reg) {
        int o = wv * 16 + grp * 4 + reg;
        size_t obase = (size_t)(b * Cc + o) * HW + pix0 + r;
        out[obase + 0 * 16] = acc0[reg];
        out[obase + 1 * 16] = acc1[reg];
        out[obase + 2 * 16] = acc2[reg];
        out[obase + 3 * 16] = acc3[reg];
    }
}

// ---------------- fallback deform (CHW taps, needs only modf in ws) ----------------
__global__ __launch_bounds__(256) void deform2(
    const float* __restrict__ xin, const float* __restrict__ offm,
    const float* __restrict__ modf, const float* __restrict__ rw,
    float* __restrict__ out)
{
    __shared__ float wT[144][32];
    int o0 = blockIdx.y * 32;
    int pg = blockIdx.x * 256 + threadIdx.x;
    int b = pg / HW, pix = pg % HW;
    int ho = pix / Ww, wo = pix % Ww;

    float acc[32];
    #pragma unroll
    for (int i = 0; i < 32; ++i) acc[i] = 0.f;

    const float* xb = xin + (size_t)b * Cc * HW;

    for (int g = 0; g < Gg; ++g) {
        __syncthreads();
        for (int idx = threadIdx.x; idx < 144 * 32; idx += 256) {
            int r = idx >> 5, oo = idx & 31;
            wT[r][oo] = rw[(size_t)(o0 + oo) * 576 + g * 144 + r];
        }
        __syncthreads();
        for (int k = 0; k < 9; ++k) {
            int oyc = b * OFFC + g * 18 + 2 * k;
            float oy = offm[(size_t)oyc * HW + pix];
            float ox = offm[(size_t)(oyc + 1) * HW + pix];
            float m  = modf[(size_t)(b * MODC + g * 9 + k) * HW + pix];
            float y = oy + (float)(k / 3) + (float)(ho - 1);
            float x = ox + (float)(k % 3) + (float)(wo - 1);
            float fy = floorf(y), fx = floorf(x);
            float ly = y - fy, lx = x - fx;
            int y0 = (int)fy, x0 = (int)fx;
            bool y0v = (unsigned)y0 < (unsigned)Hh, y1v = (unsigned)(y0 + 1) < (unsigned)Hh;
            bool x0v = (unsigned)x0 < (unsigned)Ww, x1v = (unsigned)(x0 + 1) < (unsigned)Ww;
            float w00 = (y0v && x0v) ? (1.f - ly) * (1.f - lx) * m : 0.f;
            float w01 = (y0v && x1v) ? (1.f - ly) * lx * m : 0.f;
            float w10 = (y1v && x0v) ? ly * (1.f - lx) * m : 0.f;
            float w11 = (y1v && x1v) ? ly * lx * m : 0.f;
            int iy0 = min(max(y0, 0), Hh - 1), iy1 = min(max(y0 + 1, 0), Hh - 1);
            int ix0 = min(max(x0, 0), Ww - 1), ix1 = min(max(x0 + 1, 0), Ww - 1);
            int i00 = iy0 * Ww + ix0, i01 = iy0 * Ww + ix1;
            int i10 = iy1 * Ww + ix0, i11 = iy1 * Ww + ix1;

            const float* gp = xb + (size_t)(g * Cg) * HW;
            for (int c = 0; c < 16; ++c) {
                const float* plane = gp + (size_t)c * HW;
                float val = w00 * plane[i00] + w01 * plane[i01] +
                            w10 * plane[i10] + w11 * plane[i11];
                const float* wr = wT[c * 9 + k];
                #pragma unroll
                for (int oo = 0; oo < 32; ++oo) acc[oo] += val * wr[oo];
            }
        }
    }
    #pragma unroll
    for (int oo = 0; oo < 32; ++oo)
        out[(size_t)(b * Cc + o0 + oo) * HW + pix] = acc[oo];
}

extern "C" void kernel_launch(void* const* d_in, const int* in_sizes, int n_in,
                              void* d_out, int out_size, void* d_ws, size_t ws_size,
                              hipStream_t stream)
{
    const float* warp = (const float*)d_in[0];
    const float* srcp = (const float*)d_in[1];
    const float* ow   = (const float*)d_in[2];
    const float* ob   = (const float*)d_in[3];
    const float* mw   = (const float*)d_in[4];
    const float* mb   = (const float*)d_in[5];
    const float* rw   = (const float*)d_in[6];

    float* out_x   = (float*)d_out;
    float* out_off = out_x + (size_t)Bb * Cc * HW;

    const size_t nMod = (size_t)Bb * MODC * HW;      //  2,654,208 floats
    const size_t nXT  = (size_t)Bb * Gg * HW * Cg;   //  4,718,592 floats
    const size_t nWpk = 64 * 576;                     // ushorts (72 KB)

    float*  modf = (float*)d_ws;
    float*  xT   = modf + nMod;
    ushort* wpk  = (ushort*)(xT + nXT);

    bool midws = ws_size >= (nMod + nXT) * sizeof(float) + nWpk * sizeof(ushort);

    int prep_grid = midws ? ROLE_D_END : ROLE_B_END;
    prep_kernel<<<prep_grid, 256, 0, stream>>>(
        warp, srcp, ow, ob, mw, mb, rw, out_off, modf, xT, wpk, (int)midws);

    if (midws) {
        deform_mfma<<<BHW / 64, 256, 0, stream>>>(xT, out_off, modf, wpk, out_x);
    } else {
        deform2<<<dim3(PT, 2), 256, 0, stream>>>(warp, out_off, modf, rw, out_x);
    }
}

// Round 10
// 287.506 us; speedup vs baseline: 1.2928x; 1.2928x over previous
//
#include <hip/hip_runtime.h>
#include <hip/hip_bf16.h>

constexpr int Bb = 2, Cc = 64, Hh = 192, Ww = 192, Gg = 4, Cg = 16;
constexpr int HW = Hh * Ww;
constexpr int BHW = Bb * HW;       // 73728
constexpr int OFFC = 72;           // G * 2 * K
constexpr int MODC = 36;           // G * K
constexpr int PT = BHW / 256;      // 288 pixel tiles (old prep)
constexpr int NPXT = BHW / 64;     // 1152 64-px tiles (mfma kernels)

// old prep roles (fallback path)
constexpr int ROLE_A_END = PT * Gg;
constexpr int ROLE_B_END = ROLE_A_END + PT * 2;
constexpr int ROLE_C_END = ROLE_B_END + PT * Gg;
constexpr int ROLE_D_END = ROLE_C_END + 144;

// prep_lite roles
constexpr int L_TW_END = 1152;             // transpose warp
constexpr int L_TS_END = L_TW_END + 1152;  // transpose src
constexpr int L_PW_END = L_TS_END + 144;   // pack deform W
constexpr int L_PM_END = L_PW_END + 144;   // pack mod W
constexpr int L_PO_END = L_PM_END + 36;    // pack off W

constexpr int ROWB = 1168;         // LDS row pitch bytes per pixel (576 bf16 + pad)

typedef __attribute__((ext_vector_type(8))) short short8;
typedef __attribute__((ext_vector_type(4))) float f32x4;

__device__ __forceinline__ float sigm(float x) { return 1.f / (1.f + __expf(-x)); }
__device__ __forceinline__ ushort f2bf(float f) {
    __hip_bfloat16 h = __float2bfloat16(f);
    union { __hip_bfloat16 h; ushort u; } x; x.h = h; return x.u;
}

__device__ __forceinline__ void transpose_role(const float* __restrict__ src0,
                                               float* __restrict__ dstT, int vb)
{
    int tid = vb * 256 + threadIdx.x;   // over B*G*HW
    int pix = tid % HW;
    int bg = tid / HW;
    int b = bg >> 2, g = bg & 3;
    const float* src = src0 + (size_t)(b * Cc + g * Cg) * HW + pix;
    float4* dst = (float4*)(dstT + (size_t)tid * 16);
    #pragma unroll
    for (int c4 = 0; c4 < 4; ++c4) {
        float4 v;
        v.x = src[(size_t)(c4 * 4 + 0) * HW];
        v.y = src[(size_t)(c4 * 4 + 1) * HW];
        v.z = src[(size_t)(c4 * 4 + 2) * HW];
        v.w = src[(size_t)(c4 * 4 + 3) * HW];
        dst[c4] = v;
    }
}

// ---------------- prep_lite: transposes + weight packs ----------------
__global__ __launch_bounds__(256) void prep_lite(
    const float* __restrict__ warp, const float* __restrict__ srcp,
    const float* __restrict__ rw, const float* __restrict__ mw,
    const float* __restrict__ ow,
    float* __restrict__ xT, float* __restrict__ xT2,
    ushort* __restrict__ wpk, ushort* __restrict__ amod, ushort* __restrict__ aoff)
{
    int vb = blockIdx.x;
    if (vb < L_TW_END) {
        transpose_role(warp, xT, vb);
    } else if (vb < L_TS_END) {
        transpose_role(srcp, xT2, vb - L_TW_END);
    } else if (vb < L_PW_END) {
        // pack deform reg_w: apack[((w*18+s)*64+l)*8+e] = rw[o=w*16+(l&15)][j=s*32+(l>>4)*8+e]
        int t = (vb - L_TS_END) * 256 + threadIdx.x;   // 36864
        if (t >= 64 * 576) return;
        int o = t / 576, jp = t % 576;
        int gk = jp >> 4, c = jp & 15;
        int g = gk / 9, k = gk % 9;
        float f = rw[(size_t)o * 576 + g * 144 + c * 9 + k];
        int w = o >> 4;
        int l = (o & 15) + (((jp & 31) >> 3) << 4);
        int s = jp >> 5, e = jp & 7;
        wpk[(((size_t)(w * 18 + s)) * 64 + l) * 8 + e] = f2bf(f);
    } else if (vb < L_PM_END) {
        // pack mod weights, M pad 64 (4 tiles), K=576, j=(chunk*144 + k*16 + c)
        int t = (vb - L_PW_END) * 256 + threadIdx.x;   // 36864
        if (t >= 4 * 18 * 64 * 8) return;
        int e = t & 7, l = (t >> 3) & 63, ms = t >> 9;  // ms = m*18+s
        int m = ms / 18, s = ms % 18;
        int row = m * 16 + (l & 15);
        int j = s * 32 + ((l >> 4) << 3) + e;
        int chunk = j / 144, rr = j % 144, k = rr >> 4, c = rr & 15;
        int ic = chunk * 16 + c;
        float f = (row < MODC) ? mw[(size_t)row * 576 + ic * 9 + k] : 0.f;
        amod[t] = f2bf(f);
    } else {
        // pack offset weights, M pad 32 (2 tiles), K=288, j=(half*144 + k*16 + c)
        int t = (vb - L_PM_END) * 256 + threadIdx.x;   // 9216
        if (t >= 2 * 9 * 64 * 8) return;
        int e = t & 7, l = (t >> 3) & 63, ms = t >> 9;  // ms = m*9+s
        int m = ms / 9, s = ms % 9;
        int row = m * 16 + (l & 15);
        int j = s * 32 + ((l >> 4) << 3) + e;
        int half = j / 144, rr = j % 144, k = rr >> 4, c = rr & 15;
        float f = (row < 18) ? ow[(size_t)row * 288 + (half * 16 + c) * 9 + k] : 0.f;
        aoff[t] = f2bf(f);
    }
}

// ---------------- conv via MFMA: mod (vb<NPXT) / offset (vb>=NPXT) ----------------
__global__ __launch_bounds__(256) void conv_mfma(
    const float* __restrict__ xT, const float* __restrict__ xT2,
    const ushort* __restrict__ amod, const ushort* __restrict__ aoff,
    const float* __restrict__ mb, const float* __restrict__ ob,
    float* __restrict__ modf, float* __restrict__ off_out)
{
    __shared__ char Ps[64 * ROWB];   // 74.75 KB
    int lane = threadIdx.x & 63, wv = threadIdx.x >> 6;
    int vb = blockIdx.x;
    bool isoff = vb >= NPXT;
    int pt = isoff ? vb - NPXT : vb;
    int px0 = pt * 64;
    int b = px0 / HW, pix0 = px0 % HW;
    int pix = pix0 + lane;
    int ho = pix / Ww, wo = pix % Ww;
    int r = lane & 15, grp = lane >> 4;

    if (!isoff) {
        // ---- MOD CONV: stage warp patch, chunk = wv (16 ch) ----
        const float* xg = xT + (size_t)((b << 2) + wv) * HW * 16;
        #pragma unroll
        for (int k = 0; k < 9; ++k) {
            int iy = ho + k / 3 - 1, ix = wo + k % 3 - 1;
            bool v = ((unsigned)iy < (unsigned)Hh) && ((unsigned)ix < (unsigned)Ww);
            float4 t0, t1, t2, t3;
            if (v) {
                const float4* tp = (const float4*)(xg + (size_t)(iy * Ww + ix) * 16);
                t0 = tp[0]; t1 = tp[1]; t2 = tp[2]; t3 = tp[3];
            } else {
                t0.x=t0.y=t0.z=t0.w=0.f; t1=t0; t2=t0; t3=t0;
            }
            short8 v0, v1;
            v0[0]=(short)f2bf(t0.x); v0[1]=(short)f2bf(t0.y); v0[2]=(short)f2bf(t0.z); v0[3]=(short)f2bf(t0.w);
            v0[4]=(short)f2bf(t1.x); v0[5]=(short)f2bf(t1.y); v0[6]=(short)f2bf(t1.z); v0[7]=(short)f2bf(t1.w);
            v1[0]=(short)f2bf(t2.x); v1[1]=(short)f2bf(t2.y); v1[2]=(short)f2bf(t2.z); v1[3]=(short)f2bf(t2.w);
            v1[4]=(short)f2bf(t3.x); v1[5]=(short)f2bf(t3.y); v1[6]=(short)f2bf(t3.z); v1[7]=(short)f2bf(t3.w);
            char* dst = Ps + (size_t)lane * ROWB + wv * 288 + k * 32;
            *(short8*)dst = v0;
            *(short8*)(dst + 16) = v1;
        }
        __syncthreads();
        // ---- GEMM: 12 jobs (3 Mtiles x 4 Ntiles), wave does 3 ----
        f32x4 accA = {0,0,0,0}, accB = accA, accC = accA;
        #pragma unroll
        for (int q = 0; q < 3; ++q) {
            int jid = wv * 3 + q;
            int m = jid >> 2, n = jid & 3;
            const char* bbase = Ps + (size_t)(n * 16 + r) * ROWB + grp * 16;
            const ushort* abase = amod + ((size_t)(m * 18) * 64 + lane) * 8;
            f32x4 acc = {0,0,0,0};
            #pragma unroll
            for (int s = 0; s < 18; ++s) {
                short8 a = *(const short8*)(abase + (size_t)s * 512);
                short8 bb = *(const short8*)(bbase + s * 64);
                acc = __builtin_amdgcn_mfma_f32_16x16x32_bf16(a, bb, acc, 0, 0, 0);
            }
            if (q == 0) accA = acc; else if (q == 1) accB = acc; else accC = acc;
        }
        #pragma unroll
        for (int q = 0; q < 3; ++q) {
            int jid = wv * 3 + q;
            int m = jid >> 2, n = jid & 3;
            f32x4 acc = (q == 0) ? accA : (q == 1) ? accB : accC;
            #pragma unroll
            for (int reg = 0; reg < 4; ++reg) {
                int oc = m * 16 + grp * 4 + reg;
                if (oc < MODC)
                    modf[(size_t)(b * MODC + oc) * HW + pix0 + n * 16 + r] =
                        2.f * sigm(acc[reg] + mb[oc]);
            }
        }
    } else {
        // ---- OFFSET CONV: two passes over g-pairs ----
        int gg = wv >> 1, half = wv & 1;
        for (int pass = 0; pass < 2; ++pass) {
            if (pass) __syncthreads();
            int g = pass * 2 + gg;
            const float* xg = (half ? xT2 : xT) + (size_t)((b << 2) + g) * HW * 16;
            #pragma unroll
            for (int k = 0; k < 9; ++k) {
                int iy = ho + k / 3 - 1, ix = wo + k % 3 - 1;
                bool v = ((unsigned)iy < (unsigned)Hh) && ((unsigned)ix < (unsigned)Ww);
                float4 t0, t1, t2, t3;
                if (v) {
                    const float4* tp = (const float4*)(xg + (size_t)(iy * Ww + ix) * 16);
                    t0 = tp[0]; t1 = tp[1]; t2 = tp[2]; t3 = tp[3];
                } else {
                    t0.x=t0.y=t0.z=t0.w=0.f; t1=t0; t2=t0; t3=t0;
                }
                short8 v0, v1;
                v0[0]=(short)f2bf(t0.x); v0[1]=(short)f2bf(t0.y); v0[2]=(short)f2bf(t0.z); v0[3]=(short)f2bf(t0.w);
                v0[4]=(short)f2bf(t1.x); v0[5]=(short)f2bf(t1.y); v0[6]=(short)f2bf(t1.z); v0[7]=(short)f2bf(t1.w);
                v1[0]=(short)f2bf(t2.x); v1[1]=(short)f2bf(t2.y); v1[2]=(short)f2bf(t2.z); v1[3]=(short)f2bf(t2.w);
                v1[4]=(short)f2bf(t3.x); v1[5]=(short)f2bf(t3.y); v1[6]=(short)f2bf(t3.z); v1[7]=(short)f2bf(t3.w);
                char* dst = Ps + (size_t)lane * ROWB + gg * 576 + half * 288 + k * 32;
                *(short8*)dst = v0;
                *(short8*)(dst + 16) = v1;
            }
            __syncthreads();
            // 16 jobs (2 g x 2 Mtiles x 4 Ntiles), wave does 4
            #pragma unroll
            for (int q = 0; q < 4; ++q) {
                int jid = wv * 4 + q;
                int jg = jid >> 3, mt = (jid >> 2) & 1, n = jid & 3;
                const char* bbase = Ps + (size_t)(n * 16 + r) * ROWB + jg * 576 + grp * 16;
                const ushort* abase = aoff + ((size_t)(mt * 9) * 64 + lane) * 8;
                f32x4 acc = {0,0,0,0};
                #pragma unroll
                for (int s = 0; s < 9; ++s) {
                    short8 a = *(const short8*)(abase + (size_t)s * 512);
                    short8 bb = *(const short8*)(bbase + s * 64);
                    acc = __builtin_amdgcn_mfma_f32_16x16x32_bf16(a, bb, acc, 0, 0, 0);
                }
                int g2 = pass * 2 + jg;
                #pragma unroll
                for (int reg = 0; reg < 4; ++reg) {
                    int ocl = mt * 16 + grp * 4 + reg;
                    if (ocl < 18)
                        off_out[(size_t)(b * OFFC + g2 * 18 + ocl) * HW + pix0 + n * 16 + r] =
                            100.f * sigm(acc[reg] + ob[ocl]) - 50.f;
                }
            }
        }
    }
}

// ---------------- deformable conv: f32 sampling -> LDS bf16 -> MFMA GEMM ----------------
__global__ __launch_bounds__(256) void deform_mfma(
    const float* __restrict__ xT, const float* __restrict__ offm,
    const float* __restrict__ modf, const ushort* __restrict__ wpk,
    float* __restrict__ out)
{
    __shared__ char Vs[64 * ROWB];
    int lane = threadIdx.x & 63;
    int wv = threadIdx.x >> 6;
    int px0 = blockIdx.x * 64;
    int b = px0 / HW, pix0 = px0 % HW;

    short8 afrag[18];
    #pragma unroll
    for (int s = 0; s < 18; ++s)
        afrag[s] = *(const short8*)(wpk + (((size_t)(wv * 18 + s)) * 64 + lane) * 8);

    {
        int pix = pix0 + lane;
        int ho = pix / Ww, wo = pix % Ww;
        int g = wv;
        const float* xg = xT + (size_t)((b << 2) + g) * HW * 16;

        for (int k = 0; k < 9; ++k) {
            int oyc = b * OFFC + g * 18 + 2 * k;
            float oy = offm[(size_t)oyc * HW + pix];
            float ox = offm[(size_t)(oyc + 1) * HW + pix];
            float m  = modf[(size_t)(b * MODC + g * 9 + k) * HW + pix];
            float y = oy + (float)(k / 3) + (float)(ho - 1);
            float x = ox + (float)(k % 3) + (float)(wo - 1);
            float fy = floorf(y), fx = floorf(x);
            float ly = y - fy, lx = x - fx;
            int y0 = (int)fy, x0 = (int)fx;
            bool y0v = (unsigned)y0 < (unsigned)Hh, y1v = (unsigned)(y0 + 1) < (unsigned)Hh;
            bool x0v = (unsigned)x0 < (unsigned)Ww, x1v = (unsigned)(x0 + 1) < (unsigned)Ww;
            float w00 = (y0v && x0v) ? (1.f - ly) * (1.f - lx) * m : 0.f;
            float w01 = (y0v && x1v) ? (1.f - ly) * lx * m : 0.f;
            float w10 = (y1v && x0v) ? ly * (1.f - lx) * m : 0.f;
            float w11 = (y1v && x1v) ? ly * lx * m : 0.f;
            int iy0 = min(max(y0, 0), Hh - 1), iy1 = min(max(y0 + 1, 0), Hh - 1);
            int ix0 = min(max(x0, 0), Ww - 1), ix1 = min(max(x0 + 1, 0), Ww - 1);

            const float4* t00 = (const float4*)(xg + (size_t)(iy0 * Ww + ix0) * 16);
            const float4* t01 = (const float4*)(xg + (size_t)(iy0 * Ww + ix1) * 16);
            const float4* t10 = (const float4*)(xg + (size_t)(iy1 * Ww + ix0) * 16);
            const float4* t11 = (const float4*)(xg + (size_t)(iy1 * Ww + ix1) * 16);

            float val[16];
            #pragma unroll
            for (int c4 = 0; c4 < 4; ++c4) {
                float4 a = t00[c4], b2 = t01[c4], c2 = t10[c4], d2 = t11[c4];
                val[c4 * 4 + 0] = w00 * a.x + w01 * b2.x + w10 * c2.x + w11 * d2.x;
                val[c4 * 4 + 1] = w00 * a.y + w01 * b2.y + w10 * c2.y + w11 * d2.y;
                val[c4 * 4 + 2] = w00 * a.z + w01 * b2.z + w10 * c2.z + w11 * d2.z;
                val[c4 * 4 + 3] = w00 * a.w + w01 * b2.w + w10 * c2.w + w11 * d2.w;
            }

            short8 v0, v1;
            #pragma unroll
            for (int e = 0; e < 8; ++e) {
                v0[e] = (short)f2bf(val[e]);
                v1[e] = (short)f2bf(val[8 + e]);
            }
            int gk = g * 9 + k;
            char* dst = Vs + (size_t)lane * ROWB + gk * 32;
            *(short8*)(dst)      = v0;
            *(short8*)(dst + 16) = v1;
        }
    }
    __syncthreads();

    int r = lane & 15, grp = lane >> 4;
    f32x4 acc0 = {0.f, 0.f, 0.f, 0.f}, acc1 = acc0, acc2 = acc0, acc3 = acc0;

    #pragma unroll
    for (int s = 0; s < 18; ++s) {
        const char* base = Vs + (size_t)r * ROWB + s * 64 + grp * 16;
        short8 b0 = *(const short8*)(base + 0 * 16 * ROWB);
        short8 b1 = *(const short8*)(base + 1 * 16 * ROWB);
        short8 b2 = *(const short8*)(base + 2 * 16 * ROWB);
        short8 b3 = *(const short8*)(base + 3 * 16 * ROWB);
        acc0 = __builtin_amdgcn_mfma_f32_16x16x32_bf16(afrag[s], b0, acc0, 0, 0, 0);
        acc1 = __builtin_amdgcn_mfma_f32_16x16x32_bf16(afrag[s], b1, acc1, 0, 0, 0);
        acc2 = __builtin_amdgcn_mfma_f32_16x16x32_bf16(afrag[s], b2, acc2, 0, 0, 0);
        acc3 = __builtin_amdgcn_mfma_f32_16x16x32_bf16(afrag[s], b3, acc3, 0, 0, 0);
    }

    #pragma unroll
    for (int reg = 0; reg < 4; ++reg) {
        int o = wv * 16 + grp * 4 + reg;
        size_t obase = (size_t)(b * Cc + o) * HW + pix0 + r;
        out[obase + 0 * 16] = acc0[reg];
        out[obase + 1 * 16] = acc1[reg];
        out[obase + 2 * 16] = acc2[reg];
        out[obase + 3 * 16] = acc3[reg];
    }
}

// ---------------- OLD fused prep (fallback only) ----------------
__global__ __launch_bounds__(256) void prep_kernel(
    const float* __restrict__ warp, const float* __restrict__ srcp,
    const float* __restrict__ ow, const float* __restrict__ ob,
    const float* __restrict__ mw, const float* __restrict__ mb,
    const float* __restrict__ rw,
    float* __restrict__ off_out, float* __restrict__ modf,
    float* __restrict__ xT, ushort* __restrict__ wpk, int do_xT)
{
    __shared__ float smem[144 * 20];
    int vb = blockIdx.x;

    if (vb < ROLE_A_END) {
        float (*wT)[20] = (float(*)[20])smem;
        int g = vb / PT;
        int pg = (vb % PT) * 256 + threadIdx.x;
        int b = pg / HW, pix = pg % HW;
        int ho = pix / Ww, wo = pix % Ww;

        int  tidx[9];
        bool tv[9];
        #pragma unroll
        for (int kh = 0; kh < 3; ++kh)
            #pragma unroll
            for (int kw = 0; kw < 3; ++kw) {
                int ih = ho - 1 + kh, iw = wo - 1 + kw;
                bool v = ((unsigned)ih < (unsigned)Hh) && ((unsigned)iw < (unsigned)Ww);
                tv[kh * 3 + kw] = v;
                tidx[kh * 3 + kw] = v ? ih * Ww + iw : 0;
            }

        float acc[18];
        #pragma unroll
        for (int i = 0; i < 18; ++i) acc[i] = 0.f;

        for (int half = 0; half < 2; ++half) {
            __syncthreads();
            for (int idx = threadIdx.x; idx < 144 * 18; idx += 256) {
                int r = idx / 18, oo = idx % 18;
                wT[r][oo] = ow[oo * 288 + half * 144 + r];
            }
            __syncthreads();
            const float* basep = (half ? srcp : warp) + (size_t)(b * Cc + g * Cg) * HW;
            for (int ic = 0; ic < 16; ++ic) {
                const float* plane = basep + (size_t)ic * HW;
                #pragma unroll
                for (int t = 0; t < 9; ++t) {
                    float v = tv[t] ? plane[tidx[t]] : 0.f;
                    const float* wr = wT[ic * 9 + t];
                    #pragma unroll
                    for (int oo = 0; oo < 18; ++oo) acc[oo] += v * wr[oo];
                }
            }
        }
        #pragma unroll
        for (int oo = 0; oo < 18; ++oo) {
            float s = acc[oo] + ob[oo];
            off_out[(size_t)(b * OFFC + g * 18 + oo) * HW + pix] = 100.f * sigm(s) - 50.f;
        }
    } else if (vb < ROLE_B_END) {
        float (*wT)[20] = (float(*)[20])smem;
        int vb2 = vb - ROLE_A_END;
        int c0 = (vb2 / PT) * 18;
        int pg = (vb2 % PT) * 256 + threadIdx.x;
        int b = pg / HW, pix = pg % HW;
        int ho = pix / Ww, wo = pix % Ww;

        int  tidx[9];
        bool tv[9];
        #pragma unroll
        for (int kh = 0; kh < 3; ++kh)
            #pragma unroll
            for (int kw = 0; kw < 3; ++kw) {
                int ih = ho - 1 + kh, iw = wo - 1 + kw;
                bool v = ((unsigned)ih < (unsigned)Hh) && ((unsigned)iw < (unsigned)Ww);
                tv[kh * 3 + kw] = v;
                tidx[kh * 3 + kw] = v ? ih * Ww + iw : 0;
            }

        float acc[18];
        #pragma unroll
        for (int i = 0; i < 18; ++i) acc[i] = 0.f;

        for (int q = 0; q < 4; ++q) {
            __syncthreads();
            for (int idx = threadIdx.x; idx < 144 * 18; idx += 256) {
                int r = idx / 18, oo = idx % 18;
                wT[r][oo] = mw[(size_t)(c0 + oo) * 576 + q * 144 + r];
            }
            __syncthreads();
            const float* bp = warp + (size_t)(b * Cc + q * 16) * HW;
            for (int ic = 0; ic < 16; ++ic) {
                const float* plane = bp + (size_t)ic * HW;
                #pragma unroll
                for (int t = 0; t < 9; ++t) {
                    float v = tv[t] ? plane[tidx[t]] : 0.f;
                    const float* wr = wT[ic * 9 + t];
                    #pragma unroll
                    for (int oo = 0; oo < 18; ++oo) acc[oo] += v * wr[oo];
                }
            }
        }
        #pragma unroll
        for (int oo = 0; oo < 18; ++oo)
            modf[(size_t)(b * MODC + c0 + oo) * HW + pix] = 2.f * sigm(acc[oo] + mb[c0 + oo]);
    } else if (vb < ROLE_C_END) {
        if (!do_xT) return;
        transpose_role(warp, xT, vb - ROLE_B_END);
    } else {
        if (!do_xT) return;
        int t = (vb - ROLE_C_END) * 256 + threadIdx.x;
        if (t >= 64 * 576) return;
        int o = t / 576, jp = t % 576;
        int gk = jp >> 4, c = jp & 15;
        int g = gk / 9, k = gk % 9;
        float f = rw[(size_t)o * 576 + g * 144 + c * 9 + k];
        int w = o >> 4;
        int l = (o & 15) + (((jp & 31) >> 3) << 4);
        int s = jp >> 5, e = jp & 7;
        wpk[(((size_t)(w * 18 + s)) * 64 + l) * 8 + e] = f2bf(f);
    }
}

// ---------------- fallback deform (CHW taps) ----------------
__global__ __launch_bounds__(256) void deform2(
    const float* __restrict__ xin, const float* __restrict__ offm,
    const float* __restrict__ modf, const float* __restrict__ rw,
    float* __restrict__ out)
{
    __shared__ float wT[144][32];
    int o0 = blockIdx.y * 32;
    int pg = blockIdx.x * 256 + threadIdx.x;
    int b = pg / HW, pix = pg % HW;
    int ho = pix / Ww, wo = pix % Ww;

    float acc[32];
    #pragma unroll
    for (int i = 0; i < 32; ++i) acc[i] = 0.f;

    const float* xb = xin + (size_t)b * Cc * HW;

    for (int g = 0; g < Gg; ++g) {
        __syncthreads();
        for (int idx = threadIdx.x; idx < 144 * 32; idx += 256) {
            int r = idx >> 5, oo = idx & 31;
            wT[r][oo] = rw[(size_t)(o0 + oo) * 576 + g * 144 + r];
        }
        __syncthreads();
        for (int k = 0; k < 9; ++k) {
            int oyc = b * OFFC + g * 18 + 2 * k;
            float oy = offm[(size_t)oyc * HW + pix];
            float ox = offm[(size_t)(oyc + 1) * HW + pix];
            float m  = modf[(size_t)(b * MODC + g * 9 + k) * HW + pix];
            float y = oy + (float)(k / 3) + (float)(ho - 1);
            float x = ox + (float)(k % 3) + (float)(wo - 1);
            float fy = floorf(y), fx = floorf(x);
            float ly = y - fy, lx = x - fx;
            int y0 = (int)fy, x0 = (int)fx;
            bool y0v = (unsigned)y0 < (unsigned)Hh, y1v = (unsigned)(y0 + 1) < (unsigned)Hh;
            bool x0v = (unsigned)x0 < (unsigned)Ww, x1v = (unsigned)(x0 + 1) < (unsigned)Ww;
            float w00 = (y0v && x0v) ? (1.f - ly) * (1.f - lx) * m : 0.f;
            float w01 = (y0v && x1v) ? (1.f - ly) * lx * m : 0.f;
            float w10 = (y1v && x0v) ? ly * (1.f - lx) * m : 0.f;
            float w11 = (y1v && x1v) ? ly * lx * m : 0.f;
            int iy0 = min(max(y0, 0), Hh - 1), iy1 = min(max(y0 + 1, 0), Hh - 1);
            int ix0 = min(max(x0, 0), Ww - 1), ix1 = min(max(x0 + 1, 0), Ww - 1);
            int i00 = iy0 * Ww + ix0, i01 = iy0 * Ww + ix1;
            int i10 = iy1 * Ww + ix0, i11 = iy1 * Ww + ix1;

            const float* gp = xb + (size_t)(g * Cg) * HW;
            for (int c = 0; c < 16; ++c) {
                const float* plane = gp + (size_t)c * HW;
                float val = w00 * plane[i00] + w01 * plane[i01] +
                            w10 * plane[i10] + w11 * plane[i11];
                const float* wr = wT[c * 9 + k];
                #pragma unroll
                for (int oo = 0; oo < 32; ++oo) acc[oo] += val * wr[oo];
            }
        }
    }
    #pragma unroll
    for (int oo = 0; oo < 32; ++oo)
        out[(size_t)(b * Cc + o0 + oo) * HW + pix] = acc[oo];
}

extern "C" void kernel_launch(void* const* d_in, const int* in_sizes, int n_in,
                              void* d_out, int out_size, void* d_ws, size_t ws_size,
                              hipStream_t stream)
{
    const float* warp = (const float*)d_in[0];
    const float* srcp = (const float*)d_in[1];
    const float* ow   = (const float*)d_in[2];
    const float* ob   = (const float*)d_in[3];
    const float* mw   = (const float*)d_in[4];
    const float* mb   = (const float*)d_in[5];
    const float* rw   = (const float*)d_in[6];

    float* out_x   = (float*)d_out;
    float* out_off = out_x + (size_t)Bb * Cc * HW;

    const size_t nMod = (size_t)Bb * MODC * HW;      //  2,654,208 floats
    const size_t nXT  = (size_t)Bb * Gg * HW * Cg;   //  4,718,592 floats
    const size_t nWpk = 64 * 576;                    // ushorts
    const size_t nAmod = 4 * 18 * 64 * 8;            // 36864 ushorts
    const size_t nAoff = 2 * 9 * 64 * 8;             // 9216 ushorts

    // new layout
    float*  modf = (float*)d_ws;
    float*  xT   = modf + nMod;
    float*  xT2  = xT + nXT;
    ushort* wpk  = (ushort*)(xT2 + nXT);
    ushort* amod = wpk + nWpk;
    ushort* aoff = amod + nAmod;

    size_t need_new = (nMod + 2 * nXT) * sizeof(float) +
                      (nWpk + nAmod + nAoff) * sizeof(ushort);
    size_t need_mid = (nMod + nXT) * sizeof(float) + nWpk * sizeof(ushort);

    if (ws_size >= need_new) {
        prep_lite<<<L_PO_END, 256, 0, stream>>>(warp, srcp, rw, mw, ow,
                                                xT, xT2, wpk, amod, aoff);
        conv_mfma<<<2 * NPXT, 256, 0, stream>>>(xT, xT2, amod, aoff, mb, ob,
                                                modf, out_off);
        deform_mfma<<<NPXT, 256, 0, stream>>>(xT, out_off, modf, wpk, out_x);
    } else if (ws_size >= need_mid) {
        // old layout: modf, xT, wpk
        ushort* wpk2 = (ushort*)(xT + nXT);
        prep_kernel<<<ROLE_D_END, 256, 0, stream>>>(
            warp, srcp, ow, ob, mw, mb, rw, out_off, modf, xT, wpk2, 1);
        deform_mfma<<<NPXT, 256, 0, stream>>>(xT, out_off, modf, wpk2, out_x);
    } else {
        prep_kernel<<<ROLE_B_END, 256, 0, stream>>>(
            warp, srcp, ow, ob, mw, mb, rw, out_off, modf, xT, wpk, 0);
        deform2<<<dim3(PT, 2), 256, 0, stream>>>(warp, out_off, modf, rw, out_x);
    }
}